// Round 3
// baseline (459.213 us; speedup 1.0000x reference)
//
#include <hip/hip_runtime.h>
#include <hip/hip_bf16.h>

typedef __attribute__((ext_vector_type(8))) short short8;
typedef __attribute__((ext_vector_type(4))) short short4v;
typedef __attribute__((ext_vector_type(4))) float floatx4;

#define NND 8192
#define DHID 512
#define TAU_INV 2.0f
#define CEXP 2.885390081777927f
#define E2 7.389056098930650f

__device__ inline unsigned short f2bf(float f) {
    union { float f; unsigned u; } v; v.f = f;
    unsigned r = v.u + 0x7FFFu + ((v.u >> 16) & 1u);
    return (unsigned short)(r >> 16);
}
__device__ inline float bf2f(short s) {
    union { unsigned u; float f; } v; v.u = ((unsigned)(unsigned short)s) << 16;
    return v.f;
}

__device__ inline void gload_lds16(const short* g, short* l) {
    __builtin_amdgcn_global_load_lds(
        (const __attribute__((address_space(1))) unsigned int*)g,
        (__attribute__((address_space(3))) unsigned int*)l,
        16, 0, 0);
}

// ---------------- cast / transpose helpers ----------------

__global__ void cast_bf16(const float* __restrict__ in, short* __restrict__ out) {
    int i = blockIdx.x * 256 + threadIdx.x;
    floatx4 v0 = ((const floatx4*)in)[2 * i];
    floatx4 v1 = ((const floatx4*)in)[2 * i + 1];
    short8 o;
    o[0] = (short)f2bf(v0[0]); o[1] = (short)f2bf(v0[1]);
    o[2] = (short)f2bf(v0[2]); o[3] = (short)f2bf(v0[3]);
    o[4] = (short)f2bf(v1[0]); o[5] = (short)f2bf(v1[1]);
    o[6] = (short)f2bf(v1[2]); o[7] = (short)f2bf(v1[3]);
    ((short8*)out)[i] = o;
}

__global__ void transpose_cast(const float* __restrict__ in, short* __restrict__ out) {
    int idx = blockIdx.x * 256 + threadIdx.x;
    int n = idx >> 9, k = idx & 511;
    out[(n << 9) + k] = (short)f2bf(in[(k << 9) + n]);
}

// ---------------- projection GEMM (NT), 128x128 tile, 4 waves ----------------
// MODE 0: +bias, elu -> bf16 out ; MODE 1: +bias -> fp32 out
#define BK 32

template<int MODE>
__global__ __launch_bounds__(256, 2)
void gemm_nt(const short* __restrict__ A, const short* __restrict__ B, int N,
             const float* __restrict__ bias,
             short* __restrict__ outBf, float* __restrict__ outF)
{
    __shared__ short As[128 * BK];
    __shared__ short Bs[128 * BK];

    const int tid  = threadIdx.x;
    const int m0 = blockIdx.x * 128;
    const int n0 = blockIdx.y * 128;
    const int wave = tid >> 6;
    const int lane = tid & 63;
    const int wr   = wave >> 1;
    const int wc   = wave & 1;
    const int lrow = lane & 15;
    const int lk   = lane >> 4;
    const int swq  = (lk ^ ((lrow >> 1) & 3)) * 8;

    floatx4 acc[4][4];
    floatx4 zero4 = {0.f, 0.f, 0.f, 0.f};
#pragma unroll
    for (int m = 0; m < 4; ++m)
#pragma unroll
        for (int n = 0; n < 4; ++n) acc[m][n] = zero4;

    for (int kt = 0; kt < 512 / BK; ++kt) {
        const int k0 = kt * BK;
        __syncthreads();
#pragma unroll
        for (int i = 0; i < 2; ++i) {
            const int chunk = i * 256 + tid;
            const int r = chunk >> 2;
            const int qq = chunk & 3;
            const int q = qq ^ ((r >> 1) & 3);
            gload_lds16(A + (size_t)(m0 + r) * 512 + k0 + q * 8, &As[r * 32 + qq * 8]);
            gload_lds16(B + (size_t)(n0 + r) * 512 + k0 + q * 8, &Bs[r * 32 + qq * 8]);
        }
        __syncthreads();
        short8 fa[4], fb[4];
#pragma unroll
        for (int m = 0; m < 4; ++m)
            fa[m] = *(const short8*)(&As[(wr * 64 + m * 16 + lrow) * 32 + swq]);
#pragma unroll
        for (int n = 0; n < 4; ++n)
            fb[n] = *(const short8*)(&Bs[(wc * 64 + n * 16 + lrow) * 32 + swq]);
#pragma unroll
        for (int m = 0; m < 4; ++m)
#pragma unroll
            for (int n = 0; n < 4; ++n)
                acc[m][n] = __builtin_amdgcn_mfma_f32_16x16x32_bf16(fa[m], fb[n], acc[m][n], 0, 0, 0);
    }

#pragma unroll
    for (int m = 0; m < 4; ++m) {
#pragma unroll
        for (int n = 0; n < 4; ++n) {
            const int gj = n0 + wc * 64 + n * 16 + lrow;
            const float bj = bias[gj];
#pragma unroll
            for (int r = 0; r < 4; ++r) {
                const int gi = m0 + wr * 64 + m * 16 + lk * 4 + r;
                float v = acc[m][n][r] + bj;
                if (MODE == 0) {
                    v = v > 0.f ? v : expm1f(v);
                    outBf[(size_t)gi * N + gj] = (short)f2bf(v);
                } else {
                    outF[(size_t)gi * N + gj] = v;
                }
            }
        }
    }
}

// ---------------- similarity GEMM: 256x256 tile, 8 waves, phase-split ----------------
// exp2(c*CEXP) -> atomic row sums (+ col sums; SYM: cols also into rowsum, triangle grid)

template<bool SYM>
__global__ __launch_bounds__(512, 2)
void gemm_sim(const short* __restrict__ A, const short* __restrict__ B, int nwg,
              float* __restrict__ rowsum, float* __restrict__ colsum)
{
    __shared__ short As[2][256 * 32];
    __shared__ short Bs[2][256 * 32];

    const int tid = threadIdx.x;
    // XCD-aware bijective swizzle (nwg % 8 == 0)
    const int cpx = nwg >> 3;
    const int wg = ((int)blockIdx.x & 7) * cpx + ((int)blockIdx.x >> 3);
    int m0, n0;
    if (SYM) {
        int bi = (int)((65.0f - sqrtf(4225.0f - 8.0f * (float)wg)) * 0.5f);
        if (bi < 0) bi = 0;
        if (bi > 31) bi = 31;
        while (bi > 0 && bi * 32 - bi * (bi - 1) / 2 > wg) --bi;
        while ((bi + 1) * 32 - (bi + 1) * bi / 2 <= wg) ++bi;
        const int bj = bi + (wg - (bi * 32 - bi * (bi - 1) / 2));
        m0 = bi << 8; n0 = bj << 8;
    } else {
        m0 = (wg >> 5) << 8; n0 = (wg & 31) << 8;
    }
    const int lane = tid & 63;
    const int wave = tid >> 6;
    const int wr = wave >> 2;          // 0..1 -> 128-row half
    const int wc = wave & 3;           // 0..3 -> 64-col strip
    const int lrow = lane & 15;
    const int lk = lane >> 4;
    const int swq = (lk ^ ((lrow >> 1) & 3)) * 8;

    // staging: chunkid = pass*512 + tid; r = chunkid>>2 (+128 on pass 1); q' = chunkid&3
    const int sr = tid >> 2;           // 0..127
    const int sq = tid & 3;
    const int qoff = (sq ^ ((sr >> 1) & 3)) * 8;   // ((sr+128)>>1)&3 == (sr>>1)&3

    const short* Ag  = A + (size_t)(m0 + sr) * 512 + qoff;
    const short* Ag2 = A + (size_t)(m0 + 128 + sr) * 512 + qoff;
    const short* Bg  = B + (size_t)(n0 + sr) * 512 + qoff;
    const short* Bg2 = B + (size_t)(n0 + 128 + sr) * 512 + qoff;

#define STAGE(buf, k0) do { \
    gload_lds16(Ag  + (k0), &As[buf][ sr        * 32 + sq * 8]); \
    gload_lds16(Ag2 + (k0), &As[buf][(sr + 128) * 32 + sq * 8]); \
    gload_lds16(Bg  + (k0), &Bs[buf][ sr        * 32 + sq * 8]); \
    gload_lds16(Bg2 + (k0), &Bs[buf][(sr + 128) * 32 + sq * 8]); \
} while (0)

    floatx4 acc[8][4];
    floatx4 zero4 = {0.f, 0.f, 0.f, 0.f};
#pragma unroll
    for (int m = 0; m < 8; ++m)
#pragma unroll
        for (int n = 0; n < 4; ++n) acc[m][n] = zero4;

    STAGE(0, 0);
    asm volatile("s_waitcnt vmcnt(0)" ::: "memory");
    __builtin_amdgcn_s_barrier();

    for (int kt = 0; kt < 16; ++kt) {
        const int cur = kt & 1;
        // ---- phase 0: early-issue next stage; read B0-3 + A0-3; MFMA m0-3
        if (kt < 15) STAGE(cur ^ 1, (kt + 1) * 32);
        short8 fb[4], fa[4];
#pragma unroll
        for (int n = 0; n < 4; ++n)
            fb[n] = *(const short8*)&Bs[cur][(wc * 64 + n * 16 + lrow) * 32 + swq];
#pragma unroll
        for (int m = 0; m < 4; ++m)
            fa[m] = *(const short8*)&As[cur][(wr * 128 + m * 16 + lrow) * 32 + swq];
        __builtin_amdgcn_s_barrier();
        __builtin_amdgcn_s_setprio(1);
#pragma unroll
        for (int m = 0; m < 4; ++m)
#pragma unroll
            for (int n = 0; n < 4; ++n)
                acc[m][n] = __builtin_amdgcn_mfma_f32_16x16x32_bf16(fa[m], fb[n], acc[m][n], 0, 0, 0);
        __builtin_amdgcn_s_setprio(0);
        __builtin_amdgcn_s_barrier();
        // ---- phase 1: read A4-7; MFMA m4-7
#pragma unroll
        for (int m = 0; m < 4; ++m)
            fa[m] = *(const short8*)&As[cur][(wr * 128 + (m + 4) * 16 + lrow) * 32 + swq];
        __builtin_amdgcn_s_setprio(1);
#pragma unroll
        for (int m = 0; m < 4; ++m)
#pragma unroll
            for (int n = 0; n < 4; ++n)
                acc[m + 4][n] = __builtin_amdgcn_mfma_f32_16x16x32_bf16(fa[m], fb[n], acc[m + 4][n], 0, 0, 0);
        __builtin_amdgcn_s_setprio(0);
        // ---- K-tile boundary: drain this tile's stage, then flip
        asm volatile("s_waitcnt vmcnt(0)" ::: "memory");
        __builtin_amdgcn_s_barrier();
    }
#undef STAGE

    // epilogue: exp2 + row/col sums
    float colpart[4] = {0.f, 0.f, 0.f, 0.f};
#pragma unroll
    for (int m = 0; m < 8; ++m) {
        float rowpart[4] = {0.f, 0.f, 0.f, 0.f};
#pragma unroll
        for (int n = 0; n < 4; ++n) {
#pragma unroll
            for (int r = 0; r < 4; ++r) {
                float v = exp2f(acc[m][n][r] * CEXP);
                rowpart[r] += v;
                colpart[n] += v;
            }
        }
#pragma unroll
        for (int r = 0; r < 4; ++r) {
            float t = rowpart[r];
            t += __shfl_xor(t, 1);
            t += __shfl_xor(t, 2);
            t += __shfl_xor(t, 4);
            t += __shfl_xor(t, 8);
            if (lrow == 0) atomicAdd(&rowsum[m0 + wr * 128 + m * 16 + lk * 4 + r], t);
        }
    }
    const bool wantcol = SYM ? (m0 != n0) : true;
    if (wantcol) {
        float* ctgt = SYM ? rowsum : colsum;
#pragma unroll
        for (int n = 0; n < 4; ++n) {
            float t = colpart[n];
            t += __shfl_xor(t, 16);
            t += __shfl_xor(t, 32);
            if (lk == 0) atomicAdd(&ctgt[n0 + wc * 64 + n * 16 + lrow], t);
        }
    }
}

// ---------------- row-normalize fp32 -> bf16 ----------------
__global__ void normalize_rows(const float* __restrict__ o, short* __restrict__ an) {
    const int row = blockIdx.x;
    const int t = threadIdx.x;
    floatx4 v = ((const floatx4*)(o + ((size_t)row << 9)))[t];
    float ss = v[0]*v[0] + v[1]*v[1] + v[2]*v[2] + v[3]*v[3];
    for (int m = 1; m < 64; m <<= 1) ss += __shfl_xor(ss, m);
    __shared__ float part[2];
    if ((t & 63) == 0) part[t >> 6] = ss;
    __syncthreads();
    const float sc = 1.f / fmaxf(sqrtf(part[0] + part[1]), 1e-12f);
    short4v o4;
    o4[0] = (short)f2bf(v[0] * sc); o4[1] = (short)f2bf(v[1] * sc);
    o4[2] = (short)f2bf(v[2] * sc); o4[3] = (short)f2bf(v[3] * sc);
    ((short4v*)(an + ((size_t)row << 9)))[t] = o4;
}

// ---------------- per-row dot(an1_i, an2_i) ----------------
__global__ void diag_dot(const short* __restrict__ a, const short* __restrict__ b,
                         float* __restrict__ d) {
    const int row = blockIdx.x * 4 + (threadIdx.x >> 6);
    const int lane = threadIdx.x & 63;
    const short8 x = *(const short8*)(a + ((size_t)row << 9) + lane * 8);
    const short8 y = *(const short8*)(b + ((size_t)row << 9) + lane * 8);
    float s = 0.f;
#pragma unroll
    for (int j = 0; j < 8; ++j) s += bf2f(x[j]) * bf2f(y[j]);
    for (int m = 1; m < 64; m <<= 1) s += __shfl_xor(s, m);
    if (lane == 0) d[row] = s;
}

// ---------------- final loss reduction ----------------
__global__ void final_reduce(const float* __restrict__ r1, const float* __restrict__ r2,
                             const float* __restrict__ brow, const float* __restrict__ bcol,
                             const float* __restrict__ d12, float* __restrict__ out) {
    float s = 0.f;
    for (int i = threadIdx.x; i < NND; i += 256) {
        const float den1 = r1[i] + brow[i] - E2;
        const float den2 = r2[i] + bcol[i] - E2;
        s += 0.5f * (logf(den1) + logf(den2)) - d12[i] * TAU_INV;
    }
    for (int m = 1; m < 64; m <<= 1) s += __shfl_xor(s, m);
    __shared__ float part[4];
    const int lane = threadIdx.x & 63, w = threadIdx.x >> 6;
    if (lane == 0) part[w] = s;
    __syncthreads();
    if (threadIdx.x == 0) out[0] = (part[0] + part[1] + part[2] + part[3]) / (float)NND;
}

// ---------------- launch ----------------
extern "C" void kernel_launch(void* const* d_in, const int* in_sizes, int n_in,
                              void* d_out, int out_size, void* d_ws, size_t ws_size,
                              hipStream_t stream) {
    const float* z1 = (const float*)d_in[0];
    const float* z2 = (const float*)d_in[1];
    const float* w1 = (const float*)d_in[3];
    const float* b1 = (const float*)d_in[4];
    const float* w2 = (const float*)d_in[5];
    const float* b2 = (const float*)d_in[6];
    float* out = (float*)d_out;

    char* p = (char*)d_ws;
    const size_t MATB = (size_t)NND * DHID * 2;
    short* an1 = (short*)p;  p += MATB;
    short* an2 = (short*)p;  p += MATB;
    short* zb  = (short*)p;  p += MATB;
    short* hb  = (short*)p;  p += MATB;
    float* obuf = (float*)p; p += (size_t)NND * DHID * 4;
    short* w1t = (short*)p;  p += 512 * 512 * 2;
    short* w2t = (short*)p;  p += 512 * 512 * 2;
    float* r1  = (float*)p;  p += NND * 4;
    float* r2  = (float*)p;  p += NND * 4;
    float* brow = (float*)p; p += NND * 4;
    float* bcol = (float*)p; p += NND * 4;
    float* d12 = (float*)p;  p += NND * 4;
    if ((size_t)(p - (char*)d_ws) > ws_size) return;

    hipMemsetAsync(r1, 0, (size_t)NND * 4 * 4, stream);

    transpose_cast<<<1024, 256, 0, stream>>>(w1, w1t);
    transpose_cast<<<1024, 256, 0, stream>>>(w2, w2t);

    cast_bf16<<<2048, 256, 0, stream>>>(z1, zb);
    gemm_nt<0><<<dim3(64, 4), 256, 0, stream>>>(zb, w1t, 512, b1, hb, nullptr);
    gemm_nt<1><<<dim3(64, 4), 256, 0, stream>>>(hb, w2t, 512, b2, nullptr, obuf);
    normalize_rows<<<NND, 128, 0, stream>>>(obuf, an1);

    cast_bf16<<<2048, 256, 0, stream>>>(z2, zb);
    gemm_nt<0><<<dim3(64, 4), 256, 0, stream>>>(zb, w1t, 512, b1, hb, nullptr);
    gemm_nt<1><<<dim3(64, 4), 256, 0, stream>>>(hb, w2t, 512, b2, nullptr, obuf);
    normalize_rows<<<NND, 128, 0, stream>>>(obuf, an2);

    diag_dot<<<NND / 4, 256, 0, stream>>>(an1, an2, d12);

    gemm_sim<true><<<528, 512, 0, stream>>>(an1, an1, 528, r1, nullptr);
    gemm_sim<true><<<528, 512, 0, stream>>>(an2, an2, 528, r2, nullptr);
    gemm_sim<false><<<1024, 512, 0, stream>>>(an1, an2, 1024, brow, bcol);

    final_reduce<<<1, 256, 0, stream>>>(r1, r2, brow, bcol, d12, out);
}

// Round 4
// 286.370 us; speedup vs baseline: 1.6036x; 1.6036x over previous
//
#include <hip/hip_runtime.h>
#include <hip/hip_bf16.h>

typedef __attribute__((ext_vector_type(8))) short short8;
typedef __attribute__((ext_vector_type(4))) short short4v;
typedef __attribute__((ext_vector_type(4))) float floatx4;

#define NND 8192
#define DHID 512
#define TAU_INV 2.0f
#define CEXP 2.885390081777927f
#define E2 7.389056098930650f

__device__ inline unsigned short f2bf(float f) {
    union { float f; unsigned u; } v; v.f = f;
    unsigned r = v.u + 0x7FFFu + ((v.u >> 16) & 1u);
    return (unsigned short)(r >> 16);
}
__device__ inline float bf2f(short s) {
    union { unsigned u; float f; } v; v.u = ((unsigned)(unsigned short)s) << 16;
    return v.f;
}

__device__ inline void gload_lds16(const void* g, void* l) {
    __builtin_amdgcn_global_load_lds(
        (const __attribute__((address_space(1))) unsigned int*)g,
        (__attribute__((address_space(3))) unsigned int*)l,
        16, 0, 0);
}

// ---------------- cast / transpose helpers ----------------

__global__ void cast_bf16(const float* __restrict__ in, short* __restrict__ out) {
    int i = blockIdx.x * 256 + threadIdx.x;
    floatx4 v0 = ((const floatx4*)in)[2 * i];
    floatx4 v1 = ((const floatx4*)in)[2 * i + 1];
    short8 o;
    o[0] = (short)f2bf(v0[0]); o[1] = (short)f2bf(v0[1]);
    o[2] = (short)f2bf(v0[2]); o[3] = (short)f2bf(v0[3]);
    o[4] = (short)f2bf(v1[0]); o[5] = (short)f2bf(v1[1]);
    o[6] = (short)f2bf(v1[2]); o[7] = (short)f2bf(v1[3]);
    ((short8*)out)[i] = o;
}

// both weights in one launch: [K=512][N=512] -> out[n][k] bf16
__global__ void transpose_cast2(const float* __restrict__ a, const float* __restrict__ b,
                                short* __restrict__ oa, short* __restrict__ ob) {
    int idx = blockIdx.x * 256 + threadIdx.x;
    const float* in = (idx < 262144) ? a : b;
    short* out = (idx < 262144) ? oa : ob;
    idx &= 262143;
    int n = idx >> 9, k = idx & 511;
    out[(n << 9) + k] = (short)f2bf(in[(k << 9) + n]);
}

// ---------------- projection GEMM (NT, bf16), 128x128 tile, 4 waves ----------------
#define BK 32

template<int MODE>   // 0: +bias,elu -> bf16 ; 1: +bias -> fp32
__global__ __launch_bounds__(256, 2)
void gemm_nt(const short* __restrict__ A, const short* __restrict__ B, int N,
             const float* __restrict__ bias,
             short* __restrict__ outBf, float* __restrict__ outF)
{
    __shared__ short As[128 * BK];
    __shared__ short Bs[128 * BK];

    const int tid  = threadIdx.x;
    const int m0 = blockIdx.x * 128;
    const int n0 = blockIdx.y * 128;
    const int wave = tid >> 6;
    const int lane = tid & 63;
    const int wr   = wave >> 1;
    const int wc   = wave & 1;
    const int lrow = lane & 15;
    const int lk   = lane >> 4;
    const int swq  = (lk ^ ((lrow >> 1) & 3)) * 8;

    floatx4 acc[4][4];
    floatx4 zero4 = {0.f, 0.f, 0.f, 0.f};
#pragma unroll
    for (int m = 0; m < 4; ++m)
#pragma unroll
        for (int n = 0; n < 4; ++n) acc[m][n] = zero4;

    for (int kt = 0; kt < 512 / BK; ++kt) {
        const int k0 = kt * BK;
        __syncthreads();
#pragma unroll
        for (int i = 0; i < 2; ++i) {
            const int chunk = i * 256 + tid;
            const int r = chunk >> 2;
            const int qq = chunk & 3;
            const int q = qq ^ ((r >> 1) & 3);
            gload_lds16(A + (size_t)(m0 + r) * 512 + k0 + q * 8, &As[r * 32 + qq * 8]);
            gload_lds16(B + (size_t)(n0 + r) * 512 + k0 + q * 8, &Bs[r * 32 + qq * 8]);
        }
        __syncthreads();
        short8 fa[4], fb[4];
#pragma unroll
        for (int m = 0; m < 4; ++m)
            fa[m] = *(const short8*)(&As[(wr * 64 + m * 16 + lrow) * 32 + swq]);
#pragma unroll
        for (int n = 0; n < 4; ++n)
            fb[n] = *(const short8*)(&Bs[(wc * 64 + n * 16 + lrow) * 32 + swq]);
#pragma unroll
        for (int m = 0; m < 4; ++m)
#pragma unroll
            for (int n = 0; n < 4; ++n)
                acc[m][n] = __builtin_amdgcn_mfma_f32_16x16x32_bf16(fa[m], fb[n], acc[m][n], 0, 0, 0);
    }

#pragma unroll
    for (int m = 0; m < 4; ++m) {
#pragma unroll
        for (int n = 0; n < 4; ++n) {
            const int gj = n0 + wc * 64 + n * 16 + lrow;
            const float bj = bias[gj];
#pragma unroll
            for (int r = 0; r < 4; ++r) {
                const int gi = m0 + wr * 64 + m * 16 + lk * 4 + r;
                float v = acc[m][n][r] + bj;
                if (MODE == 0) {
                    v = v > 0.f ? v : expm1f(v);
                    outBf[(size_t)gi * N + gj] = (short)f2bf(v);
                } else {
                    outF[(size_t)gi * N + gj] = v;
                }
            }
        }
    }
}

// ---------------- similarity GEMM (fp8 e4m3), 128x128 tile, BK=64 elems ----------------
// exp2(c*CEXP) -> atomic row sums (+ col sums; SYM: cols into rowsum, triangle grid)

template<bool SYM>
__global__ __launch_bounds__(256, 2)
void gemm_sim(const unsigned char* __restrict__ A, const unsigned char* __restrict__ B,
              float* __restrict__ rowsum, float* __restrict__ colsum)
{
    __shared__ unsigned char As[128 * 64];
    __shared__ unsigned char Bs[128 * 64];

    const int tid = threadIdx.x;
    int m0, n0;
    if (SYM) {
        const int t = blockIdx.x;
        int bi = (int)((129.0f - sqrtf(129.0f * 129.0f - 8.0f * (float)t)) * 0.5f);
        if (bi < 0) bi = 0;
        if (bi > 63) bi = 63;
        while (bi > 0 && bi * 64 - bi * (bi - 1) / 2 > t) --bi;
        while ((bi + 1) * 64 - (bi + 1) * bi / 2 <= t) ++bi;
        const int bj = bi + (t - (bi * 64 - bi * (bi - 1) / 2));
        m0 = bi * 128; n0 = bj * 128;
    } else {
        m0 = blockIdx.x * 128;
        n0 = blockIdx.y * 128;
    }
    const int wave = tid >> 6;
    const int lane = tid & 63;
    const int wr   = wave >> 1;
    const int wc   = wave & 1;
    const int lrow = lane & 15;
    const int lk   = lane >> 4;

    floatx4 acc[4][4];
    floatx4 zero4 = {0.f, 0.f, 0.f, 0.f};
#pragma unroll
    for (int m = 0; m < 4; ++m)
#pragma unroll
        for (int n = 0; n < 4; ++n) acc[m][n] = zero4;

    for (int kt = 0; kt < 8; ++kt) {
        const int k0 = kt * 64;
        __syncthreads();
        // stage 128x64B per matrix; LDS chunk (r,qL) holds global (r, qL ^ ((r>>1)&3))
#pragma unroll
        for (int pass = 0; pass < 2; ++pass) {
            const int r  = pass * 64 + (tid >> 2);
            const int qL = tid & 3;
            const int qG = qL ^ ((r >> 1) & 3);
            gload_lds16(A + (size_t)(m0 + r) * 512 + k0 + qG * 16, &As[r * 64 + qL * 16]);
            gload_lds16(B + (size_t)(n0 + r) * 512 + k0 + qG * 16, &Bs[r * 64 + qL * 16]);
        }
        __syncthreads();
        // B fragments: 4 n x 2 ksub (held), A streamed per m
        long fb[4][2];
#pragma unroll
        for (int n = 0; n < 4; ++n) {
            const int row = wc * 64 + n * 16 + lrow;
            const int sw = (row >> 1) & 3;
#pragma unroll
            for (int s = 0; s < 2; ++s) {
                const int q8 = lk + 4 * s;
                fb[n][s] = *(const long*)&Bs[row * 64 + (((q8 >> 1) ^ sw) << 4) + ((q8 & 1) << 3)];
            }
        }
#pragma unroll
        for (int m = 0; m < 4; ++m) {
            const int row = wr * 64 + m * 16 + lrow;
            const int sw = (row >> 1) & 3;
            long fa[2];
#pragma unroll
            for (int s = 0; s < 2; ++s) {
                const int q8 = lk + 4 * s;
                fa[s] = *(const long*)&As[row * 64 + (((q8 >> 1) ^ sw) << 4) + ((q8 & 1) << 3)];
            }
#pragma unroll
            for (int s = 0; s < 2; ++s)
#pragma unroll
                for (int n = 0; n < 4; ++n)
                    acc[m][n] = __builtin_amdgcn_mfma_f32_16x16x32_fp8_fp8(fa[s], fb[n][s], acc[m][n], 0, 0, 0);
        }
    }

    // epilogue: exp2 + row/col sums
    float colpart[4] = {0.f, 0.f, 0.f, 0.f};
#pragma unroll
    for (int m = 0; m < 4; ++m) {
        float rowpart[4] = {0.f, 0.f, 0.f, 0.f};
#pragma unroll
        for (int n = 0; n < 4; ++n) {
#pragma unroll
            for (int r = 0; r < 4; ++r) {
                float v = exp2f(acc[m][n][r] * CEXP);
                rowpart[r] += v;
                colpart[n] += v;
            }
        }
#pragma unroll
        for (int r = 0; r < 4; ++r) {
            float t = rowpart[r];
            t += __shfl_xor(t, 1);
            t += __shfl_xor(t, 2);
            t += __shfl_xor(t, 4);
            t += __shfl_xor(t, 8);
            if (lrow == 0) atomicAdd(&rowsum[m0 + wr * 64 + m * 16 + lk * 4 + r], t);
        }
    }
    const bool wantcol = SYM ? (m0 != n0) : true;
    if (wantcol) {
        float* ctgt = SYM ? rowsum : colsum;
#pragma unroll
        for (int n = 0; n < 4; ++n) {
            float t = colpart[n];
            t += __shfl_xor(t, 16);
            t += __shfl_xor(t, 32);
            if (lk == 0) atomicAdd(&ctgt[n0 + wc * 64 + n * 16 + lrow], t);
        }
    }
}

// ---------------- row-normalize fp32 -> bf16 + fp8 ----------------
__global__ void normalize_rows(const float* __restrict__ o, short* __restrict__ an,
                               unsigned char* __restrict__ anq) {
    const int row = blockIdx.x;
    const int t = threadIdx.x;   // 128 threads x 4 elems
    floatx4 v = ((const floatx4*)(o + ((size_t)row << 9)))[t];
    float ss = v[0]*v[0] + v[1]*v[1] + v[2]*v[2] + v[3]*v[3];
    for (int m = 1; m < 64; m <<= 1) ss += __shfl_xor(ss, m);
    __shared__ float part[2];
    if ((t & 63) == 0) part[t >> 6] = ss;
    __syncthreads();
    const float sc = 1.f / fmaxf(sqrtf(part[0] + part[1]), 1e-12f);
    const float s0 = v[0] * sc, s1 = v[1] * sc, s2 = v[2] * sc, s3 = v[3] * sc;
    short4v o4;
    o4[0] = (short)f2bf(s0); o4[1] = (short)f2bf(s1);
    o4[2] = (short)f2bf(s2); o4[3] = (short)f2bf(s3);
    ((short4v*)(an + ((size_t)row << 9)))[t] = o4;
    int w = __builtin_amdgcn_cvt_pk_fp8_f32(s0, s1, 0, false);
    w = __builtin_amdgcn_cvt_pk_fp8_f32(s2, s3, w, true);
    ((int*)(anq + ((size_t)row << 9)))[t] = w;
}

// ---------------- per-row dot(an1_i, an2_i) ----------------
__global__ void diag_dot(const short* __restrict__ a, const short* __restrict__ b,
                         float* __restrict__ d) {
    const int row = blockIdx.x * 4 + (threadIdx.x >> 6);
    const int lane = threadIdx.x & 63;
    const short8 x = *(const short8*)(a + ((size_t)row << 9) + lane * 8);
    const short8 y = *(const short8*)(b + ((size_t)row << 9) + lane * 8);
    float s = 0.f;
#pragma unroll
    for (int j = 0; j < 8; ++j) s += bf2f(x[j]) * bf2f(y[j]);
    for (int m = 1; m < 64; m <<= 1) s += __shfl_xor(s, m);
    if (lane == 0) d[row] = s;
}

// ---------------- final loss reduction ----------------
__global__ void final_reduce(const float* __restrict__ r1, const float* __restrict__ r2,
                             const float* __restrict__ brow, const float* __restrict__ bcol,
                             const float* __restrict__ d12, float* __restrict__ out) {
    float s = 0.f;
    for (int i = threadIdx.x; i < NND; i += 256) {
        const float den1 = r1[i] + brow[i] - E2;
        const float den2 = r2[i] + bcol[i] - E2;
        s += 0.5f * (logf(den1) + logf(den2)) - d12[i] * TAU_INV;
    }
    for (int m = 1; m < 64; m <<= 1) s += __shfl_xor(s, m);
    __shared__ float part[4];
    const int lane = threadIdx.x & 63, w = threadIdx.x >> 6;
    if (lane == 0) part[w] = s;
    __syncthreads();
    if (threadIdx.x == 0) out[0] = (part[0] + part[1] + part[2] + part[3]) / (float)NND;
}

// ---------------- launch ----------------
extern "C" void kernel_launch(void* const* d_in, const int* in_sizes, int n_in,
                              void* d_out, int out_size, void* d_ws, size_t ws_size,
                              hipStream_t stream) {
    const float* z1 = (const float*)d_in[0];
    const float* z2 = (const float*)d_in[1];
    const float* w1 = (const float*)d_in[3];
    const float* b1 = (const float*)d_in[4];
    const float* w2 = (const float*)d_in[5];
    const float* b2 = (const float*)d_in[6];
    float* out = (float*)d_out;

    char* p = (char*)d_ws;
    const size_t MATB = (size_t)NND * DHID * 2;
    short* an1 = (short*)p;  p += MATB;
    short* an2 = (short*)p;  p += MATB;
    short* zb  = (short*)p;  p += MATB;
    short* hb  = (short*)p;  p += MATB;
    float* obuf = (float*)p; p += (size_t)NND * DHID * 4;
    unsigned char* anq1 = (unsigned char*)p; p += (size_t)NND * DHID;
    unsigned char* anq2 = (unsigned char*)p; p += (size_t)NND * DHID;
    short* w1t = (short*)p;  p += 512 * 512 * 2;
    short* w2t = (short*)p;  p += 512 * 512 * 2;
    float* r1  = (float*)p;  p += NND * 4;
    float* r2  = (float*)p;  p += NND * 4;
    float* brow = (float*)p; p += NND * 4;
    float* bcol = (float*)p; p += NND * 4;
    float* d12 = (float*)p;  p += NND * 4;
    if ((size_t)(p - (char*)d_ws) > ws_size) return;

    hipMemsetAsync(r1, 0, (size_t)NND * 4 * 4, stream);

    transpose_cast2<<<2048, 256, 0, stream>>>(w1, w2, w1t, w2t);

    cast_bf16<<<2048, 256, 0, stream>>>(z1, zb);
    gemm_nt<0><<<dim3(64, 4), 256, 0, stream>>>(zb, w1t, 512, b1, hb, nullptr);
    gemm_nt<1><<<dim3(64, 4), 256, 0, stream>>>(hb, w2t, 512, b2, nullptr, obuf);
    normalize_rows<<<NND, 128, 0, stream>>>(obuf, an1, anq1);

    cast_bf16<<<2048, 256, 0, stream>>>(z2, zb);
    gemm_nt<0><<<dim3(64, 4), 256, 0, stream>>>(zb, w1t, 512, b1, hb, nullptr);
    gemm_nt<1><<<dim3(64, 4), 256, 0, stream>>>(hb, w2t, 512, b2, nullptr, obuf);
    normalize_rows<<<NND, 128, 0, stream>>>(obuf, an2, anq2);

    diag_dot<<<NND / 4, 256, 0, stream>>>(an1, an2, d12);

    gemm_sim<true><<<2080, 256, 0, stream>>>(anq1, anq1, r1, nullptr);
    gemm_sim<true><<<2080, 256, 0, stream>>>(anq2, anq2, r2, nullptr);
    gemm_sim<false><<<dim3(64, 64), 256, 0, stream>>>(anq1, anq2, brow, bcol);

    final_reduce<<<1, 256, 0, stream>>>(r1, r2, brow, bcol, d12, out);
}

// Round 5
// 252.427 us; speedup vs baseline: 1.8192x; 1.1345x over previous
//
#include <hip/hip_runtime.h>
#include <hip/hip_bf16.h>

typedef __attribute__((ext_vector_type(8))) short short8;
typedef __attribute__((ext_vector_type(4))) short short4v;
typedef __attribute__((ext_vector_type(4))) float floatx4;
typedef __attribute__((ext_vector_type(2))) long longx2;
typedef __attribute__((ext_vector_type(2))) unsigned int uintx2;

#define NND 8192
#define DHID 512
#define TAU_INV 2.0f
#define CEXP 2.885390081777927f
#define E2 7.389056098930650f

__device__ inline unsigned short f2bf(float f) {
    union { float f; unsigned u; } v; v.f = f;
    unsigned r = v.u + 0x7FFFu + ((v.u >> 16) & 1u);
    return (unsigned short)(r >> 16);
}
__device__ inline float bf2f(short s) {
    union { unsigned u; float f; } v; v.u = ((unsigned)(unsigned short)s) << 16;
    return v.f;
}
__device__ inline float fp8dec(unsigned b) {
    b &= 0xFF;
    const unsigned s = b >> 7, e = (b >> 3) & 15, m = b & 7;
    float v;
    if (e == 0) v = (float)m * 0.001953125f;          // m * 2^-9 (subnormal)
    else { union { unsigned u; float f; } t; t.u = ((e + 120u) << 23) | (m << 20); v = t.f; }
    return s ? -v : v;
}

__device__ inline void gload_lds16(const void* g, void* l) {
    __builtin_amdgcn_global_load_lds(
        (const __attribute__((address_space(1))) unsigned int*)g,
        (__attribute__((address_space(3))) unsigned int*)l,
        16, 0, 0);
}

// ---------------- cast both z inputs -> stacked bf16 [16384 x 512] ----------------
__global__ void cast_bf16_2(const float* __restrict__ z1, const float* __restrict__ z2,
                            short* __restrict__ out) {
    int i = blockIdx.x * 256 + threadIdx.x;      // 8 elems per thread, 1M threads
    const float* src = (i < 524288) ? z1 : z2;
    const int j = i & 524287;
    floatx4 v0 = ((const floatx4*)src)[2 * j];
    floatx4 v1 = ((const floatx4*)src)[2 * j + 1];
    short8 o;
    o[0] = (short)f2bf(v0[0]); o[1] = (short)f2bf(v0[1]);
    o[2] = (short)f2bf(v0[2]); o[3] = (short)f2bf(v0[3]);
    o[4] = (short)f2bf(v1[0]); o[5] = (short)f2bf(v1[1]);
    o[6] = (short)f2bf(v1[2]); o[7] = (short)f2bf(v1[3]);
    ((short8*)out)[i] = o;
}

// both weights in one launch: [K=512][N=512] -> out[n][k] bf16
__global__ void transpose_cast2(const float* __restrict__ a, const float* __restrict__ b,
                                short* __restrict__ oa, short* __restrict__ ob) {
    int idx = blockIdx.x * 256 + threadIdx.x;
    const float* in = (idx < 262144) ? a : b;
    short* out = (idx < 262144) ? oa : ob;
    idx &= 262143;
    int n = idx >> 9, k = idx & 511;
    out[(n << 9) + k] = (short)f2bf(in[(k << 9) + n]);
}

// ---------------- projection GEMM (NT, bf16), 128x128 tile, 4 waves ----------------
#define BK 32

template<int MODE>   // 0: +bias, elu -> bf16 ; 1: +bias -> bf16
__global__ __launch_bounds__(256, 2)
void gemm_nt(const short* __restrict__ A, const short* __restrict__ B, int N,
             const float* __restrict__ bias, short* __restrict__ outBf)
{
    __shared__ short As[128 * BK];
    __shared__ short Bs[128 * BK];

    const int tid  = threadIdx.x;
    const int m0 = blockIdx.x * 128;
    const int n0 = blockIdx.y * 128;
    const int wave = tid >> 6;
    const int lane = tid & 63;
    const int wr   = wave >> 1;
    const int wc   = wave & 1;
    const int lrow = lane & 15;
    const int lk   = lane >> 4;
    const int swq  = (lk ^ ((lrow >> 1) & 3)) * 8;

    floatx4 acc[4][4];
    floatx4 zero4 = {0.f, 0.f, 0.f, 0.f};
#pragma unroll
    for (int m = 0; m < 4; ++m)
#pragma unroll
        for (int n = 0; n < 4; ++n) acc[m][n] = zero4;

    for (int kt = 0; kt < 512 / BK; ++kt) {
        const int k0 = kt * BK;
        __syncthreads();
#pragma unroll
        for (int i = 0; i < 2; ++i) {
            const int chunk = i * 256 + tid;
            const int r = chunk >> 2;
            const int qq = chunk & 3;
            const int q = qq ^ ((r >> 1) & 3);
            gload_lds16(A + (size_t)(m0 + r) * 512 + k0 + q * 8, &As[r * 32 + qq * 8]);
            gload_lds16(B + (size_t)(n0 + r) * 512 + k0 + q * 8, &Bs[r * 32 + qq * 8]);
        }
        __syncthreads();
        short8 fa[4], fb[4];
#pragma unroll
        for (int m = 0; m < 4; ++m)
            fa[m] = *(const short8*)(&As[(wr * 64 + m * 16 + lrow) * 32 + swq]);
#pragma unroll
        for (int n = 0; n < 4; ++n)
            fb[n] = *(const short8*)(&Bs[(wc * 64 + n * 16 + lrow) * 32 + swq]);
#pragma unroll
        for (int m = 0; m < 4; ++m)
#pragma unroll
            for (int n = 0; n < 4; ++n)
                acc[m][n] = __builtin_amdgcn_mfma_f32_16x16x32_bf16(fa[m], fb[n], acc[m][n], 0, 0, 0);
    }

#pragma unroll
    for (int m = 0; m < 4; ++m) {
#pragma unroll
        for (int n = 0; n < 4; ++n) {
            const int gj = n0 + wc * 64 + n * 16 + lrow;
            const float bj = bias[gj];
#pragma unroll
            for (int r = 0; r < 4; ++r) {
                const int gi = m0 + wr * 64 + m * 16 + lk * 4 + r;
                float v = acc[m][n][r] + bj;
                if (MODE == 0) v = v > 0.f ? v : expm1f(v);
                outBf[(size_t)gi * N + gj] = (short)f2bf(v);
            }
        }
    }
}

// ---------------- similarity GEMM (fp8 e4m3, k-permuted rows), 128x128, BK=64 ----------------
// exp2(c*CEXP) -> atomic row sums (+ col sums; SYM: cols into rowsum, triangle grid)

template<bool SYM>
__global__ __launch_bounds__(256, 2)
void gemm_sim(const unsigned char* __restrict__ A, const unsigned char* __restrict__ B,
              float* __restrict__ rowsum, float* __restrict__ colsum)
{
    __shared__ unsigned char As[128 * 64];
    __shared__ unsigned char Bs[128 * 64];

    const int tid = threadIdx.x;
    int m0, n0;
    if (SYM) {
        const int t = blockIdx.x;
        int bi = (int)((129.0f - sqrtf(129.0f * 129.0f - 8.0f * (float)t)) * 0.5f);
        if (bi < 0) bi = 0;
        if (bi > 63) bi = 63;
        while (bi > 0 && bi * 64 - bi * (bi - 1) / 2 > t) --bi;
        while ((bi + 1) * 64 - (bi + 1) * bi / 2 <= t) ++bi;
        const int bj = bi + (t - (bi * 64 - bi * (bi - 1) / 2));
        m0 = bi * 128; n0 = bj * 128;
    } else {
        m0 = blockIdx.x * 128;
        n0 = blockIdx.y * 128;
    }
    const int wave = tid >> 6;
    const int lane = tid & 63;
    const int wr   = wave >> 1;
    const int wc   = wave & 1;
    const int lrow = lane & 15;
    const int lk   = lane >> 4;

    floatx4 acc[4][4];
    floatx4 zero4 = {0.f, 0.f, 0.f, 0.f};
#pragma unroll
    for (int m = 0; m < 4; ++m)
#pragma unroll
        for (int n = 0; n < 4; ++n) acc[m][n] = zero4;

    for (int kt = 0; kt < 8; ++kt) {
        const int k0 = kt * 64;
        __syncthreads();
#pragma unroll
        for (int pass = 0; pass < 2; ++pass) {
            const int r  = pass * 64 + (tid >> 2);
            const int qL = tid & 3;
            const int qG = qL ^ ((r >> 1) & 3);
            gload_lds16(A + (size_t)(m0 + r) * 512 + k0 + qG * 16, &As[r * 64 + qL * 16]);
            gload_lds16(B + (size_t)(n0 + r) * 512 + k0 + qG * 16, &Bs[r * 64 + qL * 16]);
        }
        __syncthreads();
        // one b128 per fragment: granule lk holds this lane's k-chunk for both K=32 sub-steps
        longx2 fb[4];
#pragma unroll
        for (int n = 0; n < 4; ++n) {
            const int row = wc * 64 + n * 16 + lrow;
            fb[n] = *(const longx2*)&Bs[(row << 6) + ((lk ^ ((row >> 1) & 3)) << 4)];
        }
#pragma unroll
        for (int m = 0; m < 4; ++m) {
            const int row = wr * 64 + m * 16 + lrow;
            const longx2 fa = *(const longx2*)&As[(row << 6) + ((lk ^ ((row >> 1) & 3)) << 4)];
#pragma unroll
            for (int n = 0; n < 4; ++n) {
                acc[m][n] = __builtin_amdgcn_mfma_f32_16x16x32_fp8_fp8(fa[0], fb[n][0], acc[m][n], 0, 0, 0);
                acc[m][n] = __builtin_amdgcn_mfma_f32_16x16x32_fp8_fp8(fa[1], fb[n][1], acc[m][n], 0, 0, 0);
            }
        }
    }

    // epilogue: exp2 + row/col sums
    float colpart[4] = {0.f, 0.f, 0.f, 0.f};
#pragma unroll
    for (int m = 0; m < 4; ++m) {
        float rowpart[4] = {0.f, 0.f, 0.f, 0.f};
#pragma unroll
        for (int n = 0; n < 4; ++n) {
#pragma unroll
            for (int r = 0; r < 4; ++r) {
                float v = exp2f(acc[m][n][r] * CEXP);
                rowpart[r] += v;
                colpart[n] += v;
            }
        }
#pragma unroll
        for (int r = 0; r < 4; ++r) {
            float t = rowpart[r];
            t += __shfl_xor(t, 1);
            t += __shfl_xor(t, 2);
            t += __shfl_xor(t, 4);
            t += __shfl_xor(t, 8);
            if (lrow == 0) atomicAdd(&rowsum[m0 + wr * 64 + m * 16 + lk * 4 + r], t);
        }
    }
    const bool wantcol = SYM ? (m0 != n0) : true;
    if (wantcol) {
        float* ctgt = SYM ? rowsum : colsum;
#pragma unroll
        for (int n = 0; n < 4; ++n) {
            float t = colpart[n];
            t += __shfl_xor(t, 16);
            t += __shfl_xor(t, 32);
            if (lk == 0) atomicAdd(&ctgt[n0 + wc * 64 + n * 16 + lrow], t);
        }
    }
}

// ---------------- row-normalize bf16 -> fp8 (k-permuted layout) ----------------
__global__ void normalize_rows(const short* __restrict__ o, unsigned char* __restrict__ anq) {
    const int row = blockIdx.x;
    const int t = threadIdx.x;   // 128 threads x 4 elems
    short4v v4 = ((const short4v*)(o + ((size_t)row << 9)))[t];
    const float a0 = bf2f(v4[0]), a1 = bf2f(v4[1]), a2 = bf2f(v4[2]), a3 = bf2f(v4[3]);
    float ss = a0 * a0 + a1 * a1 + a2 * a2 + a3 * a3;
    for (int m = 1; m < 64; m <<= 1) ss += __shfl_xor(ss, m);
    __shared__ float part[2];
    if ((t & 63) == 0) part[t >> 6] = ss;
    __syncthreads();
    const float sc = 1.f / fmaxf(sqrtf(part[0] + part[1]), 1e-12f);
    int w = __builtin_amdgcn_cvt_pk_fp8_f32(a0 * sc, a1 * sc, 0, false);
    w = __builtin_amdgcn_cvt_pk_fp8_f32(a2 * sc, a3 * sc, w, true);
    // permuted store: k-tile b (64), within: s = kk>>5, granule g = (kk&31)>>3, o = kk&7
    const int k = t * 4;
    const int b = k >> 6, kk = k & 63;
    const int addr = (row << 9) + (b << 6) + (((kk & 31) >> 3) << 4) + ((kk >> 5) << 3) + (kk & 7);
    *(int*)(anq + addr) = w;
}

// ---------------- per-row dot(an1_i, an2_i) from fp8 (same perm both rows) ----------------
__global__ void diag_dot(const unsigned char* __restrict__ q, float* __restrict__ d) {
    const int row = blockIdx.x * 4 + (threadIdx.x >> 6);
    const int lane = threadIdx.x & 63;
    uintx2 x = *(const uintx2*)(q + ((size_t)row << 9) + lane * 8);
    uintx2 y = *(const uintx2*)(q + ((size_t)(row + NND) << 9) + lane * 8);
    float s = 0.f;
#pragma unroll
    for (int w = 0; w < 2; ++w)
#pragma unroll
        for (int j = 0; j < 4; ++j)
            s += fp8dec(x[w] >> (8 * j)) * fp8dec(y[w] >> (8 * j));
    for (int m = 1; m < 64; m <<= 1) s += __shfl_xor(s, m);
    if (lane == 0) d[row] = s;
}

// ---------------- final loss reduction ----------------
__global__ void final_reduce(const float* __restrict__ r1, const float* __restrict__ r2,
                             const float* __restrict__ brow, const float* __restrict__ bcol,
                             const float* __restrict__ d12, float* __restrict__ out) {
    float s = 0.f;
    for (int i = threadIdx.x; i < NND; i += 256) {
        const float den1 = r1[i] + brow[i] - E2;
        const float den2 = r2[i] + bcol[i] - E2;
        s += 0.5f * (logf(den1) + logf(den2)) - d12[i] * TAU_INV;
    }
    for (int m = 1; m < 64; m <<= 1) s += __shfl_xor(s, m);
    __shared__ float part[4];
    const int lane = threadIdx.x & 63, w = threadIdx.x >> 6;
    if (lane == 0) part[w] = s;
    __syncthreads();
    if (threadIdx.x == 0) out[0] = (part[0] + part[1] + part[2] + part[3]) / (float)NND;
}

// ---------------- launch ----------------
extern "C" void kernel_launch(void* const* d_in, const int* in_sizes, int n_in,
                              void* d_out, int out_size, void* d_ws, size_t ws_size,
                              hipStream_t stream) {
    const float* z1 = (const float*)d_in[0];
    const float* z2 = (const float*)d_in[1];
    const float* w1 = (const float*)d_in[3];
    const float* b1 = (const float*)d_in[4];
    const float* w2 = (const float*)d_in[5];
    const float* b2 = (const float*)d_in[6];
    float* out = (float*)d_out;

    char* p = (char*)d_ws;
    const size_t MATB = (size_t)2 * NND * DHID * 2;   // 16 MB stacked bf16 matrix
    short* zb  = (short*)p;  p += MATB;
    short* hb  = (short*)p;  p += MATB;
    short* obuf = (short*)p; p += MATB;
    unsigned char* anq = (unsigned char*)p; p += (size_t)2 * NND * DHID;  // stacked fp8
    short* w1t = (short*)p;  p += 512 * 512 * 2;
    short* w2t = (short*)p;  p += 512 * 512 * 2;
    float* r1  = (float*)p;  p += NND * 4;
    float* r2  = (float*)p;  p += NND * 4;
    float* brow = (float*)p; p += NND * 4;
    float* bcol = (float*)p; p += NND * 4;
    float* d12 = (float*)p;  p += NND * 4;
    if ((size_t)(p - (char*)d_ws) > ws_size) return;

    unsigned char* anq1 = anq;
    unsigned char* anq2 = anq + (size_t)NND * DHID;

    hipMemsetAsync(r1, 0, (size_t)NND * 4 * 4, stream);

    transpose_cast2<<<2048, 256, 0, stream>>>(w1, w2, w1t, w2t);
    cast_bf16_2<<<4096, 256, 0, stream>>>(z1, z2, zb);
    gemm_nt<0><<<dim3(128, 4), 256, 0, stream>>>(zb, w1t, 512, b1, hb);
    gemm_nt<1><<<dim3(128, 4), 256, 0, stream>>>(hb, w2t, 512, b2, obuf);
    normalize_rows<<<2 * NND, 128, 0, stream>>>(obuf, anq);
    diag_dot<<<NND / 4, 256, 0, stream>>>(anq, d12);

    gemm_sim<true><<<2080, 256, 0, stream>>>(anq1, anq1, r1, nullptr);
    gemm_sim<true><<<2080, 256, 0, stream>>>(anq2, anq2, r2, nullptr);
    gemm_sim<false><<<dim3(64, 64), 256, 0, stream>>>(anq1, anq2, brow, bcol);

    final_reduce<<<1, 256, 0, stream>>>(r1, r2, brow, bcol, d12, out);
}